// Round 7
// baseline (182.324 us; speedup 1.0000x reference)
//
#include <hip/hip_runtime.h>

namespace {
constexpr int Bn = 4096;
constexpr int Ln = 2048;
constexpr float TAU = 0.85f;
constexpr float MARGIN = 0.0005f;
constexpr float RW = 0.5f;
constexpr float CW = 0.5f;

constexpr int RPB = 4;          // 4 independent waves per block, one ROW per wave
constexpr int EPL = Ln / 64;    // 32 elements per lane
static_assert(EPL == 32, "layout assumption");

typedef float f32x4 __attribute__((ext_vector_type(4)));

// One WAVE per row; no barriers, no LDS. Labels packed to a 32-bit mask
// (1 VGPR) so live state stays tiny (R5 spilled keeping 4x32 floats).
// c is recomputed from mask bits in each pass; exp recomputed in the KL
// pass (identical instruction sequence => identical values).
// r = 2c/(k+T) in [0,1] => z=r/TAU <= 1.18: exp safe without max-sub.
// sum q*log q folded: t1/esum - log(esum).
__global__ __launch_bounds__(256) void mt_row_kernel(
    const float* __restrict__ pred,
    const float* __restrict__ rerank,
    const float* __restrict__ cut,
    const float* __restrict__ labels,
    float* __restrict__ part)
{
  const int tid  = threadIdx.x;
  const int lane = tid & 63;
  const int wid  = tid >> 6;
  const int row  = blockIdx.x * RPB + wid;
  const size_t base = (size_t)row * Ln + (size_t)lane * EPL;
  const float* __restrict__ lrow = labels + base;
  const float* __restrict__ yrow = pred   + base;
  const float* __restrict__ srow = rerank + base;
  const float* __restrict__ prow = cut    + base;

  // ---- pass 1: stream labels/pred/rerank; build mask, bce, s_all, s_pos ----
  unsigned mask = 0u;
  float bce = 0.f, s_all = 0.f, s_pos = 0.f;
  #pragma unroll
  for (int c = 0; c < 8; ++c) {
    const f32x4 lv = *(const f32x4*)(lrow + 4 * c);
    const f32x4 yv = *(const f32x4*)(yrow + 4 * c);
    const f32x4 sv = *(const f32x4*)(srow + 4 * c);
    #pragma unroll
    for (int u = 0; u < 4; ++u) {
      const int j = 4 * c + u;
      const bool pos = (lv[u] == 1.f);
      mask  |= (pos ? 1u : 0u) << j;
      bce   += __logf(pos ? yv[u] : 1.f - yv[u]);
      s_all += sv[u];
      s_pos += pos ? sv[u] : 0.f;
    }
  }

  // ---- pass 2: wave scan of per-lane label counts (exact ints) ----
  const float own = (float)__builtin_popcount(mask);
  float sc = own;
  #pragma unroll
  for (int off = 1; off < 64; off <<= 1) {
    const float n = __shfl_up(sc, off, 64);
    if (lane >= off) sc += n;
  }
  const float T    = __shfl(sc, 63, 64);   // row total
  const float excl = sc - own;             // exclusive prefix, this lane

  // ---- pass 3: z = (2c/(k+T))/TAU; esum, t1 = sum e*z (no retention) ----
  float esum0 = 0.f, esum1 = 0.f, t1a = 0.f, t1b = 0.f;
  int ci = 0;
  const float kbase = (float)(lane * EPL);
  #pragma unroll
  for (int j = 0; j < EPL; ++j) {
    ci += (int)((mask >> j) & 1u);
    const float cf = excl + (float)ci;
    const float k  = kbase + (float)(j + 1);
    const float z  = __fdividef(2.f * cf, (k + T) * TAU);
    const float ev = __expf(z);
    if (j & 1) { esum1 += ev; t1b += ev * z; }
    else       { esum0 += ev; t1a += ev * z; }
  }
  float esum = esum0 + esum1;
  float t1   = t1a + t1b;

  // ---- pass 4: wave-reduce esum, t1 (interleaved) ----
  #pragma unroll
  for (int off = 32; off > 0; off >>= 1) {
    esum += __shfl_xor(esum, off, 64);
    t1   += __shfl_xor(t1,   off, 64);
  }
  const float inv = 1.f / esum;

  // ---- pass 5: single cut pass; recompute e from mask; KL terms ----
  float kl = 0.f;
  ci = 0;
  #pragma unroll
  for (int c = 0; c < 8; ++c) {
    const f32x4 pv = *(const f32x4*)(prow + 4 * c);
    #pragma unroll
    for (int u = 0; u < 4; ++u) {
      const int j = 4 * c + u;
      ci += (int)((mask >> j) & 1u);
      const float cf = excl + (float)ci;
      const float k  = kbase + (float)(j + 1);
      const float z  = __fdividef(2.f * cf, (k + T) * TAU);
      const float q  = __expf(z) * inv;
      const float p  = pv[u];
      const float pq = p + q;
      kl += p * __logf(p) - pq * __logf(pq * 0.5f);
    }
  }

  // ---- pass 6: wave-reduce 4 scalars; lane 0 writes ----
  #pragma unroll
  for (int off = 32; off > 0; off >>= 1) {
    kl    += __shfl_xor(kl,    off, 64);
    s_all += __shfl_xor(s_all, off, 64);
    s_pos += __shfl_xor(s_pos, off, 64);
    bce   += __shfl_xor(bce,   off, 64);
  }
  if (lane == 0) {
    part[0 * Bn + row] = kl + t1 * inv - __logf(esum);
    part[1 * Bn + row] = s_all;
    part[2 * Bn + row] = s_pos;
    part[3 * Bn + row] = bce;
    part[4 * Bn + row] = T;
  }
}

// Single block: reduce 4096 per-row partials in double, emit scalar.
__global__ __launch_bounds__(256) void mt_final_kernel(
    const float* __restrict__ part, float* __restrict__ out)
{
  const int tid  = threadIdx.x;
  const int lane = tid & 63;
  const int wid  = tid >> 6;
  double kl = 0, sv = 0, sp = 0, bc = 0, tt = 0;
  for (int r = tid; r < Bn; r += 256) {
    kl += (double)part[0 * Bn + r];
    sv += (double)part[1 * Bn + r];
    sp += (double)part[2 * Bn + r];
    bc += (double)part[3 * Bn + r];
    tt += (double)part[4 * Bn + r];
  }
  #pragma unroll
  for (int off = 32; off > 0; off >>= 1) {
    kl += __shfl_xor(kl, off, 64);
    sv += __shfl_xor(sv, off, 64);
    sp += __shfl_xor(sp, off, 64);
    bc += __shfl_xor(bc, off, 64);
    tt += __shfl_xor(tt, off, 64);
  }
  __shared__ double sh[4][5];
  if (lane == 0) { sh[wid][0] = kl; sh[wid][1] = sv; sh[wid][2] = sp; sh[wid][3] = bc; sh[wid][4] = tt; }
  __syncthreads();
  if (tid == 0) {
    kl = sh[0][0] + sh[1][0] + sh[2][0] + sh[3][0];
    sv = sh[0][1] + sh[1][1] + sh[2][1] + sh[3][1];
    sp = sh[0][2] + sh[1][2] + sh[2][2] + sh[3][2];
    bc = sh[0][3] + sh[1][3] + sh[2][3] + sh[3][3];
    tt = sh[0][4] + sh[1][4] + sh[2][4] + sh[3][4];
    const double total = (double)Bn * (double)Ln;
    const double posc = tt, negc = total - tt;
    double rer = (sv - sp) / negc - sp / posc + (double)MARGIN;  // neg_mean - pos_mean + margin
    if (rer < 0.0) rer = 0.0;
    rer *= (double)RW;
    const double cutl = 0.5 * kl / (double)Bn;
    const double bcel = -(bc / total) * (double)CW;
    out[0] = (float)(cutl + rer + bcel);
  }
}
} // namespace

extern "C" void kernel_launch(void* const* d_in, const int* in_sizes, int n_in,
                              void* d_out, int out_size, void* d_ws, size_t ws_size,
                              hipStream_t stream) {
  const float* pred   = (const float*)d_in[0];  // pred_y   (B,L,1)
  const float* rerank = (const float*)d_in[1];  // rerank_y (B,L,1)
  const float* cut    = (const float*)d_in[2];  // cut_y    (B,L,1)
  const float* labels = (const float*)d_in[3];  // labels   (B,L)
  float* part = (float*)d_ws;                   // 5 * Bn floats = 80 KB
  mt_row_kernel<<<Bn / RPB, 256, 0, stream>>>(pred, rerank, cut, labels, part);
  mt_final_kernel<<<1, 256, 0, stream>>>(part, (float*)d_out);
}

// Round 8
// 159.182 us; speedup vs baseline: 1.1454x; 1.1454x over previous
//
#include <hip/hip_runtime.h>

namespace {
constexpr int Bn = 4096;
constexpr int Ln = 2048;
constexpr float TAU = 0.85f;
constexpr float MARGIN = 0.0005f;
constexpr float RW = 0.5f;
constexpr float CW = 0.5f;

constexpr int RPB = 4;          // 4 independent waves per block, one ROW per wave
constexpr int NSC = Ln / 256;   // 8 superchunks of 256 elements (4 per lane)
static_assert(NSC == 8, "layout assumption");

typedef float f32x4 __attribute__((ext_vector_type(4)));

__device__ __forceinline__ int mbcnt64(unsigned long long m) {
  return (int)__builtin_amdgcn_mbcnt_hi((unsigned)(m >> 32),
              __builtin_amdgcn_mbcnt_lo((unsigned)m, 0u));
}

// One WAVE per row; zero barriers, zero LDS. INTERLEAVED layout:
// element j = J*256 + 4*lane + u  -> float4 loads are perfectly coalesced
// (1 KB contiguous per wave instruction; R7's blocked layout thrashed L1).
// Labels {0,1} -> cumsum is SCAN-FREE: per superchunk, 4 ballots; for each
// element c = base + sum_u mbcnt(ballot_u) + own-nibble prefix; base
// accumulates in a scalar. Live state ~= 1 mask VGPR + accum scalars.
// r = 2c/(k+T) in [0,1] => z = r/TAU <= 1.18: exp safe without max-sub.
// sum q*log q folded: t1/esum - log(esum). exp recomputed in KL pass.
__global__ __launch_bounds__(256) void mt_row_kernel(
    const float* __restrict__ pred,
    const float* __restrict__ rerank,
    const float* __restrict__ cut,
    const float* __restrict__ labels,
    float* __restrict__ part)
{
  const int tid  = threadIdx.x;
  const int lane = tid & 63;
  const int wid  = tid >> 6;
  const int row  = blockIdx.x * RPB + wid;
  const size_t rbase = (size_t)row * Ln;
  const int l4 = lane * 4;

  // ---- pass A: stream labels/pred/rerank; build bit-mask, bce, s_all, s_pos ----
  unsigned mask = 0u;
  float bce = 0.f, s_all = 0.f, s_pos = 0.f;
  #pragma unroll
  for (int J = 0; J < NSC; ++J) {
    const size_t off = rbase + (size_t)(J * 256 + l4);
    const f32x4 lv = *(const f32x4*)(labels + off);
    const f32x4 yv = *(const f32x4*)(pred   + off);
    const f32x4 sv = *(const f32x4*)(rerank + off);
    #pragma unroll
    for (int u = 0; u < 4; ++u) {
      const bool pos = (lv[u] == 1.f);
      mask  |= (pos ? 1u : 0u) << (4 * J + u);
      bce   += __logf(pos ? yv[u] : 1.f - yv[u]);
      s_all += sv[u];
      s_pos += pos ? sv[u] : 0.f;
    }
  }

  // ---- T: wave total of label bits (single short reduce) ----
  int tot = __builtin_popcount(mask);
  #pragma unroll
  for (int off = 32; off > 0; off >>= 1) tot += __shfl_xor(tot, off, 64);
  const float T = (float)tot;

  // ---- pass B1: esum, t1 (no loads; ballot/mbcnt cumsum, no scan) ----
  float esum = 0.f, t1 = 0.f;
  int base = 0;
  #pragma unroll
  for (int J = 0; J < NSC; ++J) {
    int cnt_lt = 0, totJ = 0;
    #pragma unroll
    for (int u = 0; u < 4; ++u) {
      const unsigned long long b = __ballot((mask >> (4 * J + u)) & 1u);
      cnt_lt += mbcnt64(b);
      totJ   += (int)__builtin_popcountll(b);
    }
    int p = 0;
    const float kb = (float)(J * 256 + l4);
    #pragma unroll
    for (int u = 0; u < 4; ++u) {
      p += (int)((mask >> (4 * J + u)) & 1u);
      const float cf = (float)(base + cnt_lt + p);
      const float k  = kb + (float)(u + 1);
      const float z  = __fdividef(2.f * cf, (k + T) * TAU);
      const float ev = __expf(z);
      esum += ev;
      t1   += ev * z;
    }
    base += totJ;
  }
  #pragma unroll
  for (int off = 32; off > 0; off >>= 1) {
    esum += __shfl_xor(esum, off, 64);
    t1   += __shfl_xor(t1,   off, 64);
  }
  const float inv = 1.f / esum;

  // ---- pass B2: cut pass; recompute e from mask; KL terms ----
  float kl = 0.f;
  base = 0;
  #pragma unroll
  for (int J = 0; J < NSC; ++J) {
    const size_t off = rbase + (size_t)(J * 256 + l4);
    const f32x4 pv = *(const f32x4*)(cut + off);
    int cnt_lt = 0, totJ = 0;
    #pragma unroll
    for (int u = 0; u < 4; ++u) {
      const unsigned long long b = __ballot((mask >> (4 * J + u)) & 1u);
      cnt_lt += mbcnt64(b);
      totJ   += (int)__builtin_popcountll(b);
    }
    int p = 0;
    const float kb = (float)(J * 256 + l4);
    #pragma unroll
    for (int u = 0; u < 4; ++u) {
      p += (int)((mask >> (4 * J + u)) & 1u);
      const float cf = (float)(base + cnt_lt + p);
      const float k  = kb + (float)(u + 1);
      const float z  = __fdividef(2.f * cf, (k + T) * TAU);
      const float q  = __expf(z) * inv;
      const float pp = pv[u];
      const float pq = pp + q;
      kl += pp * __logf(pp) - pq * __logf(pq * 0.5f);
    }
    base += totJ;
  }

  // ---- wave-reduce 4 scalars; lane 0 writes ----
  #pragma unroll
  for (int off = 32; off > 0; off >>= 1) {
    kl    += __shfl_xor(kl,    off, 64);
    s_all += __shfl_xor(s_all, off, 64);
    s_pos += __shfl_xor(s_pos, off, 64);
    bce   += __shfl_xor(bce,   off, 64);
  }
  if (lane == 0) {
    part[0 * Bn + row] = kl + t1 * inv - __logf(esum);
    part[1 * Bn + row] = s_all;
    part[2 * Bn + row] = s_pos;
    part[3 * Bn + row] = bce;
    part[4 * Bn + row] = T;
  }
}

// Single block: reduce 4096 per-row partials in double, emit scalar.
__global__ __launch_bounds__(256) void mt_final_kernel(
    const float* __restrict__ part, float* __restrict__ out)
{
  const int tid  = threadIdx.x;
  const int lane = tid & 63;
  const int wid  = tid >> 6;
  double kl = 0, sv = 0, sp = 0, bc = 0, tt = 0;
  for (int r = tid; r < Bn; r += 256) {
    kl += (double)part[0 * Bn + r];
    sv += (double)part[1 * Bn + r];
    sp += (double)part[2 * Bn + r];
    bc += (double)part[3 * Bn + r];
    tt += (double)part[4 * Bn + r];
  }
  #pragma unroll
  for (int off = 32; off > 0; off >>= 1) {
    kl += __shfl_xor(kl, off, 64);
    sv += __shfl_xor(sv, off, 64);
    sp += __shfl_xor(sp, off, 64);
    bc += __shfl_xor(bc, off, 64);
    tt += __shfl_xor(tt, off, 64);
  }
  __shared__ double sh[4][5];
  if (lane == 0) { sh[wid][0] = kl; sh[wid][1] = sv; sh[wid][2] = sp; sh[wid][3] = bc; sh[wid][4] = tt; }
  __syncthreads();
  if (tid == 0) {
    kl = sh[0][0] + sh[1][0] + sh[2][0] + sh[3][0];
    sv = sh[0][1] + sh[1][1] + sh[2][1] + sh[3][1];
    sp = sh[0][2] + sh[1][2] + sh[2][2] + sh[3][2];
    bc = sh[0][3] + sh[1][3] + sh[2][3] + sh[3][3];
    tt = sh[0][4] + sh[1][4] + sh[2][4] + sh[3][4];
    const double total = (double)Bn * (double)Ln;
    const double posc = tt, negc = total - tt;
    double rer = (sv - sp) / negc - sp / posc + (double)MARGIN;  // neg_mean - pos_mean + margin
    if (rer < 0.0) rer = 0.0;
    rer *= (double)RW;
    const double cutl = 0.5 * kl / (double)Bn;
    const double bcel = -(bc / total) * (double)CW;
    out[0] = (float)(cutl + rer + bcel);
  }
}
} // namespace

extern "C" void kernel_launch(void* const* d_in, const int* in_sizes, int n_in,
                              void* d_out, int out_size, void* d_ws, size_t ws_size,
                              hipStream_t stream) {
  const float* pred   = (const float*)d_in[0];  // pred_y   (B,L,1)
  const float* rerank = (const float*)d_in[1];  // rerank_y (B,L,1)
  const float* cut    = (const float*)d_in[2];  // cut_y    (B,L,1)
  const float* labels = (const float*)d_in[3];  // labels   (B,L)
  float* part = (float*)d_ws;                   // 5 * Bn floats = 80 KB
  mt_row_kernel<<<Bn / RPB, 256, 0, stream>>>(pred, rerank, cut, labels, part);
  mt_final_kernel<<<1, 256, 0, stream>>>(part, (float*)d_out);
}